// Round 6
// baseline (380.375 us; speedup 1.0000x reference)
//
#include <hip/hip_runtime.h>
#include <hip/hip_bf16.h>
#include <math.h>

// Problem constants
#define B_   32
#define SX_  512
#define SM_  4096
#define D_   256
#define TOPK_ 5

// GEMM tiling
#define BM 128
#define BN 128
#define BK 32

typedef _Float16 half8 __attribute__((ext_vector_type(8)));
typedef _Float16 half4 __attribute__((ext_vector_type(4)));
typedef float    f32x4 __attribute__((ext_vector_type(4)));

#define GLOBAL_AS const __attribute__((address_space(1))) void*
#define LDS_AS    __attribute__((address_space(3))) void*

// ---------------------------------------------------------------------------
// Kernel 1 (big-ws path): fused inv-norm + split-fp16 prep.
// Writes hi/lo fp16 of (row * invnorm(row) * 16). Uniform scaling preserves
// top-k order exactly. One wave per row.
// ---------------------------------------------------------------------------
__global__ __launch_bounds__(256) void prep_kernel(
    const float* __restrict__ in,
    _Float16* __restrict__ hi_out, _Float16* __restrict__ lo_out, int nrows)
{
    const int row  = blockIdx.x * 4 + (threadIdx.x >> 6);
    const int lane = threadIdx.x & 63;
    if (row >= nrows) return;
    const float4 v = *(const float4*)(in + (size_t)row * D_ + lane * 4);
    float s = v.x * v.x + v.y * v.y + v.z * v.z + v.w * v.w;
    #pragma unroll
    for (int off = 32; off > 0; off >>= 1) s += __shfl_xor(s, off);
    const float scale = 16.0f / sqrtf(s);
    const float f[4] = {v.x * scale, v.y * scale, v.z * scale, v.w * scale};
    half4 h, l;
    #pragma unroll
    for (int i = 0; i < 4; ++i) {
        h[i] = (_Float16)f[i];
        l[i] = (_Float16)(f[i] - (float)h[i]);
    }
    *(half4*)(hi_out + (size_t)row * D_ + lane * 4) = h;
    *(half4*)(lo_out + (size_t)row * D_ + lane * 4) = l;
}

// ---------------------------------------------------------------------------
// Kernel 2 (big-ws path): pure split-fp16 MFMA GEMM + row-max,
// counted-vmcnt pipelined (T3+T4): stage -> vmcnt(8) -> barrier ->
// ds_read+MFMA -> barrier. Next-buffer loads stay in flight across barriers.
// ---------------------------------------------------------------------------
__device__ __forceinline__ void stage_tiles(
    _Float16 (*ldsbuf)[BM * BK],
    const _Float16* __restrict__ ah, const _Float16* __restrict__ al,
    const _Float16* __restrict__ bh, const _Float16* __restrict__ bl,
    int k0, int wid, int lane)
{
    const int lr = lane >> 2;   // row within 16-row instr block
    const int gp = lane & 3;    // dest granule position
    #pragma unroll
    for (int j = 0; j < 2; ++j) {
        const int r  = wid * 32 + j * 16 + lr;           // local row 0..127
        const int g  = gp ^ ((r >> 1) & 3);              // source granule (read-swizzle inverse)
        const size_t so = (size_t)r * D_ + k0 + g * 8;   // fp16 elems
        const int  dof  = (wid * 32 + j * 16) * BK;      // fp16 elems, wave-uniform
        __builtin_amdgcn_global_load_lds((GLOBAL_AS)(ah + so), (LDS_AS)&ldsbuf[0][dof], 16, 0, 0);
        __builtin_amdgcn_global_load_lds((GLOBAL_AS)(al + so), (LDS_AS)&ldsbuf[1][dof], 16, 0, 0);
        __builtin_amdgcn_global_load_lds((GLOBAL_AS)(bh + so), (LDS_AS)&ldsbuf[2][dof], 16, 0, 0);
        __builtin_amdgcn_global_load_lds((GLOBAL_AS)(bl + so), (LDS_AS)&ldsbuf[3][dof], 16, 0, 0);
    }
}

__global__ __launch_bounds__(256) void gemm16_max_kernel(
    const _Float16* __restrict__ xh, const _Float16* __restrict__ xl,
    const _Float16* __restrict__ mh, const _Float16* __restrict__ ml,
    float* __restrict__ rowmax)
{
    __shared__ _Float16 lds[2][4][BM * BK];   // 64 KB (2 blocks/CU)
    __shared__ float red[2][BM];

    const int b   = blockIdx.y;
    const int m0  = blockIdx.x * BM;
    const int tid = threadIdx.x;
    const int wid = tid >> 6, lane = tid & 63;
    const int wm  = (wid >> 1) * 64;
    const int wsj = (wid & 1) * 64;
    const int fm  = lane & 15;
    const int fkc = lane >> 4;

    const _Float16* Ah  = mh + ((size_t)b * SM_ + m0) * D_;
    const _Float16* Al  = ml + ((size_t)b * SM_ + m0) * D_;
    const _Float16* Bh0 = xh + (size_t)b * SX_ * D_;
    const _Float16* Bl0 = xl + (size_t)b * SX_ * D_;

    // fragment read offsets (fp16 elems) — swizzled granule per row
    int aoff[4], boff[4];
    #pragma unroll
    for (int mt = 0; mt < 4; ++mt) {
        const int ra = wm + mt * 16 + fm;
        aoff[mt] = ra * BK + ((fkc ^ ((ra >> 1) & 3)) << 3);
    }
    #pragma unroll
    for (int st = 0; st < 4; ++st) {
        const int rb = wsj + st * 16 + fm;
        boff[st] = rb * BK + ((fkc ^ ((rb >> 1) & 3)) << 3);
    }

    float part[4][4];
    #pragma unroll
    for (int i = 0; i < 4; ++i)
        #pragma unroll
        for (int j = 0; j < 4; ++j) part[i][j] = -INFINITY;

    int buf = 0;
    stage_tiles(lds[0], Ah, Al, Bh0, Bl0, 0, wid, lane);   // 8 loads in flight

    #pragma unroll 1
    for (int sti = 0; sti < 4; ++sti) {
        f32x4 acc[4][4];
        #pragma unroll
        for (int i = 0; i < 4; ++i)
            #pragma unroll
            for (int j = 0; j < 4; ++j) acc[i][j] = (f32x4){0.f, 0.f, 0.f, 0.f};

        #pragma unroll 1
        for (int kc = 0; kc < 8; ++kc) {
            const int it = sti * 8 + kc;
            if (it + 1 < 32) {
                // issue next chunk's 8 loads, then wait only for the current
                // chunk's (the 8 older ones) — next-chunk loads stay in flight
                const int nst = (it + 1) >> 3;
                const int nk0 = ((it + 1) & 7) * BK;
                stage_tiles(lds[buf ^ 1], Ah, Al,
                            Bh0 + (size_t)nst * BN * D_, Bl0 + (size_t)nst * BN * D_,
                            nk0, wid, lane);
                asm volatile("s_waitcnt vmcnt(8)" ::: "memory");
            } else {
                asm volatile("s_waitcnt vmcnt(0)" ::: "memory");
            }
            __builtin_amdgcn_sched_barrier(0);
            __builtin_amdgcn_s_barrier();      // current buf ready for all waves

            half8 ah[4], al[4];
            #pragma unroll
            for (int mt = 0; mt < 4; ++mt) {
                ah[mt] = *(const half8*)&lds[buf][0][aoff[mt]];
                al[mt] = *(const half8*)&lds[buf][1][aoff[mt]];
            }
            __builtin_amdgcn_s_setprio(1);
            #pragma unroll
            for (int st = 0; st < 4; ++st) {
                const half8 bh = *(const half8*)&lds[buf][2][boff[st]];
                const half8 bl = *(const half8*)&lds[buf][3][boff[st]];
                #pragma unroll
                for (int mt = 0; mt < 4; ++mt)
                    acc[mt][st] = __builtin_amdgcn_mfma_f32_16x16x32_f16(ah[mt], bh, acc[mt][st], 0, 0, 0);
                #pragma unroll
                for (int mt = 0; mt < 4; ++mt)
                    acc[mt][st] = __builtin_amdgcn_mfma_f32_16x16x32_f16(ah[mt], bl, acc[mt][st], 0, 0, 0);
                #pragma unroll
                for (int mt = 0; mt < 4; ++mt)
                    acc[mt][st] = __builtin_amdgcn_mfma_f32_16x16x32_f16(al[mt], bh, acc[mt][st], 0, 0, 0);
            }
            __builtin_amdgcn_s_setprio(0);
            __builtin_amdgcn_s_barrier();      // all reads of buf done before overwrite
            buf ^= 1;
        }
        // fold this s-tile into running row-max (register-only)
        #pragma unroll
        for (int st = 0; st < 4; ++st)
            #pragma unroll
            for (int mt = 0; mt < 4; ++mt)
                #pragma unroll
                for (int j = 0; j < 4; ++j)
                    part[mt][j] = fmaxf(part[mt][j], acc[mt][st][j]);
    }

    // reduce across the 16 s-lanes
    #pragma unroll
    for (int off = 1; off < 16; off <<= 1)
        #pragma unroll
        for (int mt = 0; mt < 4; ++mt)
            #pragma unroll
            for (int j = 0; j < 4; ++j)
                part[mt][j] = fmaxf(part[mt][j], __shfl_xor(part[mt][j], off));

    if (fm == 0) {
        #pragma unroll
        for (int mt = 0; mt < 4; ++mt)
            #pragma unroll
            for (int j = 0; j < 4; ++j)
                red[wid & 1][wm + mt * 16 + fkc * 4 + j] = part[mt][j];
    }
    __syncthreads();
    if (tid < BM)
        rowmax[(size_t)b * SM_ + m0 + tid] = fmaxf(red[0][tid], red[1][tid]);
}

// ---------------------------------------------------------------------------
// Fallback path (small ws): R4 kernels, verified absmax 0 @ 168 us gemm.
// ---------------------------------------------------------------------------
__global__ __launch_bounds__(256) void invnorm_kernel(
    const float* __restrict__ in, float* __restrict__ out, int nrows)
{
    int row  = blockIdx.x * 4 + (threadIdx.x >> 6);
    int lane = threadIdx.x & 63;
    if (row >= nrows) return;
    const float4 v = *(const float4*)(in + (size_t)row * D_ + lane * 4);
    float s = v.x * v.x + v.y * v.y + v.z * v.z + v.w * v.w;
    #pragma unroll
    for (int off = 32; off > 0; off >>= 1) s += __shfl_xor(s, off);
    if (lane == 0) out[row] = 1.0f / sqrtf(s);
}

__device__ __forceinline__ int lds_off(int row, int k) {
    return row * 32 + ((((k >> 3) ^ ((row >> 1) & 3)) << 3) | (k & 7));
}

__global__ __launch_bounds__(256) void gemm_max_kernel(
    const float* __restrict__ x, const float* __restrict__ mem,
    const float* __restrict__ invnx, const float* __restrict__ invnm,
    float* __restrict__ rowmax)
{
    __shared__ union __align__(16) {
        _Float16 t[4][BM * BK];
        float red[2][BM];
    } u;

    const int b   = blockIdx.y;
    const int m0  = blockIdx.x * BM;
    const int tid = threadIdx.x;
    const int wid = tid >> 6, lane = tid & 63;
    const int wm  = (wid >> 1) * 64;
    const int wsj = (wid & 1) * 64;
    const float* memb = mem + ((size_t)b * SM_ + m0) * D_;
    const float* xb   = x   + (size_t)b * SX_ * D_;
    const int sr = tid >> 3;
    const int sc = (tid & 7) * 4;
    const int fm  = lane & 15;
    const int fkc = lane >> 4;

    float part[4][4];
    #pragma unroll
    for (int i = 0; i < 4; ++i)
        #pragma unroll
        for (int j = 0; j < 4; ++j) part[i][j] = -INFINITY;

    #pragma unroll 1
    for (int s0 = 0; s0 < SX_; s0 += BN) {
        f32x4 acc[4][4];
        #pragma unroll
        for (int i = 0; i < 4; ++i)
            #pragma unroll
            for (int j = 0; j < 4; ++j) acc[i][j] = (f32x4){0.f, 0.f, 0.f, 0.f};

        float4 ra[4], rb[4];
        #pragma unroll
        for (int p = 0; p < 4; ++p) {
            const int r = sr + 32 * p;
            ra[p] = *(const float4*)(memb + (size_t)r * D_ + sc);
            rb[p] = *(const float4*)(xb + (size_t)(s0 + r) * D_ + sc);
        }

        #pragma unroll 1
        for (int k0 = 0; k0 < D_; k0 += BK) {
            __syncthreads();
            #pragma unroll
            for (int p = 0; p < 4; ++p) {
                const int r  = sr + 32 * p;
                const int oa = lds_off(r, sc);
                half4 hi, lo;
                hi[0] = (_Float16)ra[p].x; lo[0] = (_Float16)(ra[p].x - (float)hi[0]);
                hi[1] = (_Float16)ra[p].y; lo[1] = (_Float16)(ra[p].y - (float)hi[1]);
                hi[2] = (_Float16)ra[p].z; lo[2] = (_Float16)(ra[p].z - (float)hi[2]);
                hi[3] = (_Float16)ra[p].w; lo[3] = (_Float16)(ra[p].w - (float)hi[3]);
                *(half4*)&u.t[0][oa] = hi;
                *(half4*)&u.t[1][oa] = lo;
                hi[0] = (_Float16)rb[p].x; lo[0] = (_Float16)(rb[p].x - (float)hi[0]);
                hi[1] = (_Float16)rb[p].y; lo[1] = (_Float16)(rb[p].y - (float)hi[1]);
                hi[2] = (_Float16)rb[p].z; lo[2] = (_Float16)(rb[p].z - (float)hi[2]);
                hi[3] = (_Float16)rb[p].w; lo[3] = (_Float16)(rb[p].w - (float)hi[3]);
                *(half4*)&u.t[2][oa] = hi;
                *(half4*)&u.t[3][oa] = lo;
            }
            __syncthreads();

            if (k0 + BK < D_) {
                #pragma unroll
                for (int p = 0; p < 4; ++p) {
                    const int r = sr + 32 * p;
                    ra[p] = *(const float4*)(memb + (size_t)r * D_ + k0 + BK + sc);
                    rb[p] = *(const float4*)(xb + (size_t)(s0 + r) * D_ + k0 + BK + sc);
                }
            }

            half8 ah[4], al[4];
            #pragma unroll
            for (int mt = 0; mt < 4; ++mt) {
                const int o = lds_off(wm + mt * 16 + fm, fkc * 8);
                ah[mt] = *(const half8*)&u.t[0][o];
                al[mt] = *(const half8*)&u.t[1][o];
            }
            #pragma unroll
            for (int st = 0; st < 4; ++st) {
                const int o = lds_off(wsj + st * 16 + fm, fkc * 8);
                const half8 bh = *(const half8*)&u.t[2][o];
                const half8 bl = *(const half8*)&u.t[3][o];
                #pragma unroll
                for (int mt = 0; mt < 4; ++mt)
                    acc[mt][st] = __builtin_amdgcn_mfma_f32_16x16x32_f16(ah[mt], bh, acc[mt][st], 0, 0, 0);
                #pragma unroll
                for (int mt = 0; mt < 4; ++mt)
                    acc[mt][st] = __builtin_amdgcn_mfma_f32_16x16x32_f16(ah[mt], bl, acc[mt][st], 0, 0, 0);
                #pragma unroll
                for (int mt = 0; mt < 4; ++mt)
                    acc[mt][st] = __builtin_amdgcn_mfma_f32_16x16x32_f16(al[mt], bh, acc[mt][st], 0, 0, 0);
            }
        }

        #pragma unroll
        for (int st = 0; st < 4; ++st) {
            const float sn = invnx[b * SX_ + s0 + wsj + st * 16 + fm];
            #pragma unroll
            for (int mt = 0; mt < 4; ++mt)
                #pragma unroll
                for (int j = 0; j < 4; ++j)
                    part[mt][j] = fmaxf(part[mt][j], acc[mt][st][j] * sn);
        }
    }

    #pragma unroll
    for (int off = 1; off < 16; off <<= 1)
        #pragma unroll
        for (int mt = 0; mt < 4; ++mt)
            #pragma unroll
            for (int j = 0; j < 4; ++j)
                part[mt][j] = fmaxf(part[mt][j], __shfl_xor(part[mt][j], off));

    __syncthreads();
    if (fm == 0) {
        #pragma unroll
        for (int mt = 0; mt < 4; ++mt)
            #pragma unroll
            for (int j = 0; j < 4; ++j)
                u.red[wid & 1][wm + mt * 16 + fkc * 4 + j] = part[mt][j];
    }
    __syncthreads();
    if (tid < BM) {
        const float v = fmaxf(u.red[0][tid], u.red[1][tid]);
        rowmax[(size_t)b * SM_ + m0 + tid] = v * invnm[b * SM_ + m0 + tid];
    }
}

// ---------------------------------------------------------------------------
// Kernel 3: per batch top-5 (tie -> lower index) + gather + index write.
// ---------------------------------------------------------------------------
__global__ __launch_bounds__(256) void top5_gather_kernel(
    const float* __restrict__ rowmax,
    const float* __restrict__ mem,
    float* __restrict__ out)
{
    __shared__ float vals[SM_];
    __shared__ float rv[256];
    __shared__ int   ri[256];
    __shared__ int   topidx[TOPK_];

    const int b = blockIdx.x, tid = threadIdx.x;
    const float* rm = rowmax + (size_t)b * SM_;
    for (int i = tid; i < SM_; i += 256) vals[i] = rm[i];
    __syncthreads();

    for (int k = 0; k < TOPK_; ++k) {
        float bestv = -INFINITY;
        int   besti = SM_;
        #pragma unroll
        for (int uu = 0; uu < SM_ / 256; ++uu) {
            const int idx = tid * (SM_ / 256) + uu;
            const float v = vals[idx];
            if (v > bestv) { bestv = v; besti = idx; }
        }
        rv[tid] = bestv; ri[tid] = besti;
        __syncthreads();
        for (int off = 128; off > 0; off >>= 1) {
            if (tid < off) {
                const float ov = rv[tid + off]; const int oi = ri[tid + off];
                if (ov > rv[tid] || (ov == rv[tid] && oi < ri[tid])) { rv[tid] = ov; ri[tid] = oi; }
            }
            __syncthreads();
        }
        if (tid == 0) { topidx[k] = ri[0]; vals[ri[0]] = -INFINITY; }
        __syncthreads();
    }

    const float* memb = mem + (size_t)b * SM_ * D_;
    #pragma unroll
    for (int k = 0; k < TOPK_; ++k)
        out[(size_t)k * B_ * D_ + (size_t)b * D_ + tid] = memb[(size_t)topidx[k] * D_ + tid];
    if (tid < TOPK_) out[(size_t)TOPK_ * B_ * D_ + b * TOPK_ + tid] = (float)topidx[tid];
}

// ---------------------------------------------------------------------------
extern "C" void kernel_launch(void* const* d_in, const int* in_sizes, int n_in,
                              void* d_out, int out_size, void* d_ws, size_t ws_size,
                              hipStream_t stream)
{
    const float* x   = (const float*)d_in[0];   // [32, 512, 256]
    const float* mem = (const float*)d_in[1];   // [32, 4096, 256]
    float* out = (float*)d_out;

    // big-ws layout (bytes): xh 8M | xl 8M | mh 64M | ml 64M | rowmax 512K
    const size_t XH_B = (size_t)B_ * SX_ * D_ * 2;   //  8,388,608
    const size_t MH_B = (size_t)B_ * SM_ * D_ * 2;   // 67,108,864
    const size_t NEED = 2 * XH_B + 2 * MH_B + (size_t)B_ * SM_ * 4;

    if (ws_size >= NEED) {
        char* w = (char*)d_ws;
        _Float16* xh = (_Float16*)(w);
        _Float16* xl = (_Float16*)(w + XH_B);
        _Float16* mh = (_Float16*)(w + 2 * XH_B);
        _Float16* ml = (_Float16*)(w + 2 * XH_B + MH_B);
        float* rowmax = (float*)(w + 2 * XH_B + 2 * MH_B);

        prep_kernel<<<(B_ * SX_) / 4, 256, 0, stream>>>(x, xh, xl, B_ * SX_);
        prep_kernel<<<(B_ * SM_) / 4, 256, 0, stream>>>(mem, mh, ml, B_ * SM_);

        dim3 grid(SM_ / BM, B_);
        gemm16_max_kernel<<<grid, 256, 0, stream>>>(xh, xl, mh, ml, rowmax);
        top5_gather_kernel<<<B_, 256, 0, stream>>>(rowmax, mem, out);
    } else {
        float* invnx  = (float*)d_ws;
        float* invnm  = invnx + B_ * SX_;
        float* rowmax = invnm + B_ * SM_;

        invnorm_kernel<<<(B_ * SX_) / 4, 256, 0, stream>>>(x, invnx, B_ * SX_);
        invnorm_kernel<<<(B_ * SM_) / 4, 256, 0, stream>>>(mem, invnm, B_ * SM_);
        dim3 grid(SM_ / BM, B_);
        gemm_max_kernel<<<grid, 256, 0, stream>>>(x, mem, invnx, invnm, rowmax);
        top5_gather_kernel<<<B_, 256, 0, stream>>>(rowmax, mem, out);
    }
}

// Round 7
// 344.872 us; speedup vs baseline: 1.1029x; 1.1029x over previous
//
#include <hip/hip_runtime.h>
#include <hip/hip_bf16.h>
#include <math.h>

// Problem constants
#define B_   32
#define SX_  512
#define SM_  4096
#define D_   256
#define TOPK_ 5

// GEMM tiling
#define BM 128
#define BN 128
#define BK 32

typedef _Float16 half8 __attribute__((ext_vector_type(8)));
typedef _Float16 half4 __attribute__((ext_vector_type(4)));
typedef float    f32x4 __attribute__((ext_vector_type(4)));

#define GLOBAL_AS const __attribute__((address_space(1))) void*
#define LDS_AS    __attribute__((address_space(3))) void*

// ---------------------------------------------------------------------------
// Kernel 1 (big-ws path): fused inv-norm + split-fp16 prep.
// Writes hi/lo fp16 of (row * invnorm(row) * 16). Uniform scaling preserves
// top-k order exactly. One wave per row.
// ---------------------------------------------------------------------------
__global__ __launch_bounds__(256) void prep_kernel(
    const float* __restrict__ in,
    _Float16* __restrict__ hi_out, _Float16* __restrict__ lo_out, int nrows)
{
    const int row  = blockIdx.x * 4 + (threadIdx.x >> 6);
    const int lane = threadIdx.x & 63;
    if (row >= nrows) return;
    const float4 v = *(const float4*)(in + (size_t)row * D_ + lane * 4);
    float s = v.x * v.x + v.y * v.y + v.z * v.z + v.w * v.w;
    #pragma unroll
    for (int off = 32; off > 0; off >>= 1) s += __shfl_xor(s, off);
    const float scale = 16.0f / sqrtf(s);
    const float f[4] = {v.x * scale, v.y * scale, v.z * scale, v.w * scale};
    half4 h, l;
    #pragma unroll
    for (int i = 0; i < 4; ++i) {
        h[i] = (_Float16)f[i];
        l[i] = (_Float16)(f[i] - (float)h[i]);
    }
    *(half4*)(hi_out + (size_t)row * D_ + lane * 4) = h;
    *(half4*)(lo_out + (size_t)row * D_ + lane * 4) = l;
}

// ---------------------------------------------------------------------------
// Kernel 2 (big-ws path): pure split-fp16 MFMA GEMM + row-max.
// STATIC double buffer (ldsA/ldsB named arrays, k-loop unrolled x2) so the
// compiler can prove ds_read(CUR) does not alias in-flight DMA writes (NXT)
// and our counted s_waitcnt vmcnt(8) is the binding wait (R6 post-mortem:
// runtime lds[buf] indexing forced a compiler vmcnt(0) drain per phase).
// Wait-before-barrier discipline: each wave waits its OWN current-buffer
// loads (vmcnt(8): 16 outstanding -> 8 older done), then s_barrier => all
// waves' current-buffer DMAs are complete; next-buffer loads stay in flight.
// ---------------------------------------------------------------------------

// stage one [128][BK] k-chunk of all 4 operand tiles into DST (8 loads/wave)
#define STAGE(DST, BH, BL, NK0) do {                                          \
    _Pragma("unroll")                                                         \
    for (int j_ = 0; j_ < 2; ++j_) {                                          \
        const int r_ = wid * 32 + j_ * 16 + lr;                               \
        const int g_ = gp ^ ((r_ >> 1) & 3);                                  \
        const size_t so_ = (size_t)r_ * D_ + (NK0) + g_ * 8;                  \
        const int dof_ = (wid * 32 + j_ * 16) * BK;                           \
        __builtin_amdgcn_global_load_lds((GLOBAL_AS)(Ah + so_), (LDS_AS)&DST[0][dof_], 16, 0, 0); \
        __builtin_amdgcn_global_load_lds((GLOBAL_AS)(Al + so_), (LDS_AS)&DST[1][dof_], 16, 0, 0); \
        __builtin_amdgcn_global_load_lds((GLOBAL_AS)((BH) + so_), (LDS_AS)&DST[2][dof_], 16, 0, 0); \
        __builtin_amdgcn_global_load_lds((GLOBAL_AS)((BL) + so_), (LDS_AS)&DST[3][dof_], 16, 0, 0); \
    }                                                                         \
} while (0)

#define KSTEP(CUR, NXT, IT) do {                                              \
    if ((IT) + 1 < 32) {                                                      \
        const int nst_ = ((IT) + 1) >> 3;                                     \
        const int nk0_ = (((IT) + 1) & 7) * BK;                               \
        STAGE(NXT, Bh0 + (size_t)nst_ * BN * D_, Bl0 + (size_t)nst_ * BN * D_, nk0_); \
        asm volatile("s_waitcnt vmcnt(8)" ::: "memory");                      \
    } else {                                                                  \
        asm volatile("s_waitcnt vmcnt(0)" ::: "memory");                      \
    }                                                                         \
    __builtin_amdgcn_sched_barrier(0);                                        \
    __builtin_amdgcn_s_barrier();                                             \
    __builtin_amdgcn_sched_barrier(0);                                        \
    half8 ah_[4], al_[4];                                                     \
    _Pragma("unroll")                                                         \
    for (int mt_ = 0; mt_ < 4; ++mt_) {                                       \
        ah_[mt_] = *(const half8*)&CUR[0][aoff[mt_]];                         \
        al_[mt_] = *(const half8*)&CUR[1][aoff[mt_]];                         \
    }                                                                         \
    __builtin_amdgcn_s_setprio(1);                                            \
    _Pragma("unroll")                                                         \
    for (int st_ = 0; st_ < 4; ++st_) {                                       \
        const half8 bh_ = *(const half8*)&CUR[2][boff[st_]];                  \
        const half8 bl_ = *(const half8*)&CUR[3][boff[st_]];                  \
        _Pragma("unroll")                                                     \
        for (int mt_ = 0; mt_ < 4; ++mt_)                                     \
            acc[mt_][st_] = __builtin_amdgcn_mfma_f32_16x16x32_f16(ah_[mt_], bh_, acc[mt_][st_], 0, 0, 0); \
        _Pragma("unroll")                                                     \
        for (int mt_ = 0; mt_ < 4; ++mt_)                                     \
            acc[mt_][st_] = __builtin_amdgcn_mfma_f32_16x16x32_f16(ah_[mt_], bl_, acc[mt_][st_], 0, 0, 0); \
        _Pragma("unroll")                                                     \
        for (int mt_ = 0; mt_ < 4; ++mt_)                                     \
            acc[mt_][st_] = __builtin_amdgcn_mfma_f32_16x16x32_f16(al_[mt_], bh_, acc[mt_][st_], 0, 0, 0); \
    }                                                                         \
    __builtin_amdgcn_s_setprio(0);                                            \
    __builtin_amdgcn_s_barrier();                                             \
    __builtin_amdgcn_sched_barrier(0);                                        \
} while (0)

__global__ __launch_bounds__(256) void gemm16_max_kernel(
    const _Float16* __restrict__ xh, const _Float16* __restrict__ xl,
    const _Float16* __restrict__ mh, const _Float16* __restrict__ ml,
    float* __restrict__ rowmax)
{
    __shared__ _Float16 ldsA[4][BM * BK];   // even k-chunks (32 KB)
    __shared__ _Float16 ldsB[4][BM * BK];   // odd  k-chunks (32 KB)
    __shared__ float red[2][BM];

    // bijective XCD swizzle (1024 blocks % 8 == 0): XCD k owns batches 4k..4k+3
    // -> each XCD L2 holds 4 B-panels (2 MB) instead of thrashing all 32.
    const int lin = blockIdx.y * 32 + blockIdx.x;
    const int swz = (lin & 7) * 128 + (lin >> 3);
    const int b   = swz >> 5;
    const int m0  = (swz & 31) * BM;

    const int tid = threadIdx.x;
    const int wid = tid >> 6, lane = tid & 63;
    const int wm  = (wid >> 1) * 64;
    const int wsj = (wid & 1) * 64;
    const int fm  = lane & 15;
    const int fkc = lane >> 4;
    const int lr  = lane >> 2;    // staging row within 16-row group
    const int gp  = lane & 3;     // staging dest granule

    const _Float16* Ah  = mh + ((size_t)b * SM_ + m0) * D_;
    const _Float16* Al  = ml + ((size_t)b * SM_ + m0) * D_;
    const _Float16* Bh0 = xh + (size_t)b * SX_ * D_;
    const _Float16* Bl0 = xl + (size_t)b * SX_ * D_;

    // fragment read offsets (fp16 elems) — swizzled granule per row
    int aoff[4], boff[4];
    #pragma unroll
    for (int mt = 0; mt < 4; ++mt) {
        const int ra = wm + mt * 16 + fm;
        aoff[mt] = ra * BK + ((fkc ^ ((ra >> 1) & 3)) << 3);
    }
    #pragma unroll
    for (int st = 0; st < 4; ++st) {
        const int rb = wsj + st * 16 + fm;
        boff[st] = rb * BK + ((fkc ^ ((rb >> 1) & 3)) << 3);
    }

    float part[4][4];
    #pragma unroll
    for (int i = 0; i < 4; ++i)
        #pragma unroll
        for (int j = 0; j < 4; ++j) part[i][j] = -INFINITY;

    STAGE(ldsA, Bh0, Bl0, 0);   // chunk 0 in flight

    #pragma unroll 1
    for (int sti = 0; sti < 4; ++sti) {
        f32x4 acc[4][4];
        #pragma unroll
        for (int i = 0; i < 4; ++i)
            #pragma unroll
            for (int j = 0; j < 4; ++j) acc[i][j] = (f32x4){0.f, 0.f, 0.f, 0.f};

        #pragma unroll 1
        for (int kp = 0; kp < 4; ++kp) {
            const int it = sti * 8 + kp * 2;
            KSTEP(ldsA, ldsB, it);
            KSTEP(ldsB, ldsA, it + 1);
        }
        // fold this s-tile into running row-max (register-only)
        #pragma unroll
        for (int st = 0; st < 4; ++st)
            #pragma unroll
            for (int mt = 0; mt < 4; ++mt)
                #pragma unroll
                for (int j = 0; j < 4; ++j)
                    part[mt][j] = fmaxf(part[mt][j], acc[mt][st][j]);
    }

    // reduce across the 16 s-lanes
    #pragma unroll
    for (int off = 1; off < 16; off <<= 1)
        #pragma unroll
        for (int mt = 0; mt < 4; ++mt)
            #pragma unroll
            for (int j = 0; j < 4; ++j)
                part[mt][j] = fmaxf(part[mt][j], __shfl_xor(part[mt][j], off));

    if (fm == 0) {
        #pragma unroll
        for (int mt = 0; mt < 4; ++mt)
            #pragma unroll
            for (int j = 0; j < 4; ++j)
                red[wid & 1][wm + mt * 16 + fkc * 4 + j] = part[mt][j];
    }
    __syncthreads();
    if (tid < BM)
        rowmax[(size_t)b * SM_ + m0 + tid] = fmaxf(red[0][tid], red[1][tid]);
}

// ---------------------------------------------------------------------------
// Fallback path (small ws): R4 kernels, verified absmax 0 @ 168 us gemm.
// ---------------------------------------------------------------------------
__global__ __launch_bounds__(256) void invnorm_kernel(
    const float* __restrict__ in, float* __restrict__ out, int nrows)
{
    int row  = blockIdx.x * 4 + (threadIdx.x >> 6);
    int lane = threadIdx.x & 63;
    if (row >= nrows) return;
    const float4 v = *(const float4*)(in + (size_t)row * D_ + lane * 4);
    float s = v.x * v.x + v.y * v.y + v.z * v.z + v.w * v.w;
    #pragma unroll
    for (int off = 32; off > 0; off >>= 1) s += __shfl_xor(s, off);
    if (lane == 0) out[row] = 1.0f / sqrtf(s);
}

__device__ __forceinline__ int lds_off(int row, int k) {
    return row * 32 + ((((k >> 3) ^ ((row >> 1) & 3)) << 3) | (k & 7));
}

__global__ __launch_bounds__(256) void gemm_max_kernel(
    const float* __restrict__ x, const float* __restrict__ mem,
    const float* __restrict__ invnx, const float* __restrict__ invnm,
    float* __restrict__ rowmax)
{
    __shared__ union __align__(16) {
        _Float16 t[4][BM * BK];
        float red[2][BM];
    } u;

    const int b   = blockIdx.y;
    const int m0  = blockIdx.x * BM;
    const int tid = threadIdx.x;
    const int wid = tid >> 6, lane = tid & 63;
    const int wm  = (wid >> 1) * 64;
    const int wsj = (wid & 1) * 64;
    const float* memb = mem + ((size_t)b * SM_ + m0) * D_;
    const float* xb   = x   + (size_t)b * SX_ * D_;
    const int sr = tid >> 3;
    const int sc = (tid & 7) * 4;
    const int fm  = lane & 15;
    const int fkc = lane >> 4;

    float part[4][4];
    #pragma unroll
    for (int i = 0; i < 4; ++i)
        #pragma unroll
        for (int j = 0; j < 4; ++j) part[i][j] = -INFINITY;

    #pragma unroll 1
    for (int s0 = 0; s0 < SX_; s0 += BN) {
        f32x4 acc[4][4];
        #pragma unroll
        for (int i = 0; i < 4; ++i)
            #pragma unroll
            for (int j = 0; j < 4; ++j) acc[i][j] = (f32x4){0.f, 0.f, 0.f, 0.f};

        float4 ra[4], rb[4];
        #pragma unroll
        for (int p = 0; p < 4; ++p) {
            const int r = sr + 32 * p;
            ra[p] = *(const float4*)(memb + (size_t)r * D_ + sc);
            rb[p] = *(const float4*)(xb + (size_t)(s0 + r) * D_ + sc);
        }

        #pragma unroll 1
        for (int k0 = 0; k0 < D_; k0 += BK) {
            __syncthreads();
            #pragma unroll
            for (int p = 0; p < 4; ++p) {
                const int r  = sr + 32 * p;
                const int oa = lds_off(r, sc);
                half4 hi, lo;
                hi[0] = (_Float16)ra[p].x; lo[0] = (_Float16)(ra[p].x - (float)hi[0]);
                hi[1] = (_Float16)ra[p].y; lo[1] = (_Float16)(ra[p].y - (float)hi[1]);
                hi[2] = (_Float16)ra[p].z; lo[2] = (_Float16)(ra[p].z - (float)hi[2]);
                hi[3] = (_Float16)ra[p].w; lo[3] = (_Float16)(ra[p].w - (float)hi[3]);
                *(half4*)&u.t[0][oa] = hi;
                *(half4*)&u.t[1][oa] = lo;
                hi[0] = (_Float16)rb[p].x; lo[0] = (_Float16)(rb[p].x - (float)hi[0]);
                hi[1] = (_Float16)rb[p].y; lo[1] = (_Float16)(rb[p].y - (float)hi[1]);
                hi[2] = (_Float16)rb[p].z; lo[2] = (_Float16)(rb[p].z - (float)hi[2]);
                hi[3] = (_Float16)rb[p].w; lo[3] = (_Float16)(rb[p].w - (float)hi[3]);
                *(half4*)&u.t[2][oa] = hi;
                *(half4*)&u.t[3][oa] = lo;
            }
            __syncthreads();

            if (k0 + BK < D_) {
                #pragma unroll
                for (int p = 0; p < 4; ++p) {
                    const int r = sr + 32 * p;
                    ra[p] = *(const float4*)(memb + (size_t)r * D_ + k0 + BK + sc);
                    rb[p] = *(const float4*)(xb + (size_t)(s0 + r) * D_ + k0 + BK + sc);
                }
            }

            half8 ah[4], al[4];
            #pragma unroll
            for (int mt = 0; mt < 4; ++mt) {
                const int o = lds_off(wm + mt * 16 + fm, fkc * 8);
                ah[mt] = *(const half8*)&u.t[0][o];
                al[mt] = *(const half8*)&u.t[1][o];
            }
            #pragma unroll
            for (int st = 0; st < 4; ++st) {
                const int o = lds_off(wsj + st * 16 + fm, fkc * 8);
                const half8 bh = *(const half8*)&u.t[2][o];
                const half8 bl = *(const half8*)&u.t[3][o];
                #pragma unroll
                for (int mt = 0; mt < 4; ++mt)
                    acc[mt][st] = __builtin_amdgcn_mfma_f32_16x16x32_f16(ah[mt], bh, acc[mt][st], 0, 0, 0);
                #pragma unroll
                for (int mt = 0; mt < 4; ++mt)
                    acc[mt][st] = __builtin_amdgcn_mfma_f32_16x16x32_f16(ah[mt], bl, acc[mt][st], 0, 0, 0);
                #pragma unroll
                for (int mt = 0; mt < 4; ++mt)
                    acc[mt][st] = __builtin_amdgcn_mfma_f32_16x16x32_f16(al[mt], bh, acc[mt][st], 0, 0, 0);
            }
        }

        #pragma unroll
        for (int st = 0; st < 4; ++st) {
            const float sn = invnx[b * SX_ + s0 + wsj + st * 16 + fm];
            #pragma unroll
            for (int mt = 0; mt < 4; ++mt)
                #pragma unroll
                for (int j = 0; j < 4; ++j)
                    part[mt][j] = fmaxf(part[mt][j], acc[mt][st][j] * sn);
        }
    }

    #pragma unroll
    for (int off = 1; off < 16; off <<= 1)
        #pragma unroll
        for (int mt = 0; mt < 4; ++mt)
            #pragma unroll
            for (int j = 0; j < 4; ++j)
                part[mt][j] = fmaxf(part[mt][j], __shfl_xor(part[mt][j], off));

    __syncthreads();
    if (fm == 0) {
        #pragma unroll
        for (int mt = 0; mt < 4; ++mt)
            #pragma unroll
            for (int j = 0; j < 4; ++j)
                u.red[wid & 1][wm + mt * 16 + fkc * 4 + j] = part[mt][j];
    }
    __syncthreads();
    if (tid < BM) {
        const float v = fmaxf(u.red[0][tid], u.red[1][tid]);
        rowmax[(size_t)b * SM_ + m0 + tid] = v * invnm[b * SM_ + m0 + tid];
    }
}

// ---------------------------------------------------------------------------
// Kernel 3: per batch top-5 (tie -> lower index) + gather + index write.
// ---------------------------------------------------------------------------
__global__ __launch_bounds__(256) void top5_gather_kernel(
    const float* __restrict__ rowmax,
    const float* __restrict__ mem,
    float* __restrict__ out)
{
    __shared__ float vals[SM_];
    __shared__ float rv[256];
    __shared__ int   ri[256];
    __shared__ int   topidx[TOPK_];

    const int b = blockIdx.x, tid = threadIdx.x;
    const float* rm = rowmax + (size_t)b * SM_;
    for (int i = tid; i < SM_; i += 256) vals[i] = rm[i];
    __syncthreads();

    for (int k = 0; k < TOPK_; ++k) {
        float bestv = -INFINITY;
        int   besti = SM_;
        #pragma unroll
        for (int uu = 0; uu < SM_ / 256; ++uu) {
            const int idx = tid * (SM_ / 256) + uu;
            const float v = vals[idx];
            if (v > bestv) { bestv = v; besti = idx; }
        }
        rv[tid] = bestv; ri[tid] = besti;
        __syncthreads();
        for (int off = 128; off > 0; off >>= 1) {
            if (tid < off) {
                const float ov = rv[tid + off]; const int oi = ri[tid + off];
                if (ov > rv[tid] || (ov == rv[tid] && oi < ri[tid])) { rv[tid] = ov; ri[tid] = oi; }
            }
            __syncthreads();
        }
        if (tid == 0) { topidx[k] = ri[0]; vals[ri[0]] = -INFINITY; }
        __syncthreads();
    }

    const float* memb = mem + (size_t)b * SM_ * D_;
    #pragma unroll
    for (int k = 0; k < TOPK_; ++k)
        out[(size_t)k * B_ * D_ + (size_t)b * D_ + tid] = memb[(size_t)topidx[k] * D_ + tid];
    if (tid < TOPK_) out[(size_t)TOPK_ * B_ * D_ + b * TOPK_ + tid] = (float)topidx[tid];
}

// ---------------------------------------------------------------------------
extern "C" void kernel_launch(void* const* d_in, const int* in_sizes, int n_in,
                              void* d_out, int out_size, void* d_ws, size_t ws_size,
                              hipStream_t stream)
{
    const float* x   = (const float*)d_in[0];   // [32, 512, 256]
    const float* mem = (const float*)d_in[1];   // [32, 4096, 256]
    float* out = (float*)d_out;

    // big-ws layout (bytes): xh 8M | xl 8M | mh 64M | ml 64M | rowmax 512K
    const size_t XH_B = (size_t)B_ * SX_ * D_ * 2;   //  8,388,608
    const size_t MH_B = (size_t)B_ * SM_ * D_ * 2;   // 67,108,864
    const size_t NEED = 2 * XH_B + 2 * MH_B + (size_t)B_ * SM_ * 4;

    if (ws_size >= NEED) {
        char* w = (char*)d_ws;
        _Float16* xh = (_Float16*)(w);
        _Float16* xl = (_Float16*)(w + XH_B);
        _Float16* mh = (_Float16*)(w + 2 * XH_B);
        _Float16* ml = (_Float16*)(w + 2 * XH_B + MH_B);
        float* rowmax = (float*)(w + 2 * XH_B + 2 * MH_B);

        prep_kernel<<<(B_ * SX_) / 4, 256, 0, stream>>>(x, xh, xl, B_ * SX_);
        prep_kernel<<<(B_ * SM_) / 4, 256, 0, stream>>>(mem, mh, ml, B_ * SM_);

        dim3 grid(SM_ / BM, B_);
        gemm16_max_kernel<<<grid, 256, 0, stream>>>(xh, xl, mh, ml, rowmax);
        top5_gather_kernel<<<B_, 256, 0, stream>>>(rowmax, mem, out);
    } else {
        float* invnx  = (float*)d_ws;
        float* invnm  = invnx + B_ * SX_;
        float* rowmax = invnm + B_ * SM_;

        invnorm_kernel<<<(B_ * SX_) / 4, 256, 0, stream>>>(x, invnx, B_ * SX_);
        invnorm_kernel<<<(B_ * SM_) / 4, 256, 0, stream>>>(mem, invnm, B_ * SM_);
        dim3 grid(SM_ / BM, B_);
        gemm_max_kernel<<<grid, 256, 0, stream>>>(x, mem, invnx, invnm, rowmax);
        top5_gather_kernel<<<B_, 256, 0, stream>>>(rowmax, mem, out);
    }
}